// Round 6
// baseline (132.596 us; speedup 1.0000x reference)
//
#include <hip/hip_runtime.h>
#include <hip/hip_bf16.h>

#define NBANK 32
#define DHEAD 128
#define DMODEL 2048
#define NSLOT 8192   // B*S*K = 2*1024*4
#define NTOK 2048    // B*S
#define XCROWS 1024  // padded rows per bank in compacted x (cnt ~256±spread)

typedef __attribute__((ext_vector_type(8))) short short8;
typedef __attribute__((ext_vector_type(8))) float float8;
typedef __attribute__((ext_vector_type(4))) float f32x4;

__device__ __forceinline__ unsigned short f2bf(float f) {
    union { __hip_bfloat16 h; unsigned short u; } cvt;
    cvt.h = __float2bfloat16(f);
    return cvt.u;
}
__device__ __forceinline__ float bf2f(unsigned short u) {
    union { float f; unsigned int v; } cvt;
    cvt.v = ((unsigned int)u) << 16;
    return cvt.f;
}

// Convert W (fp32, [32][128][2048]) -> bf16 in FRAGMENT-SWIZZLED layout:
//   wfrag[(((bank*128 + mt)*4 + kk)*64 + lane)*8 + v]
// holds W[bank][k][m] with m = mt*16 + (lane&15), k = kk*32 + (lane>>4)*8 + v.
__global__ void convW_kernel(const float* __restrict__ W,
                             unsigned short* __restrict__ wfrag) {
    int t = blockIdx.x * 256 + threadIdx.x;   // one thread per (bank,mt,kk,lane)
    int lane = t & 63;
    int kk = (t >> 6) & 3;
    int mt = (t >> 8) & 127;
    int bank = t >> 15;
    int m = mt * 16 + (lane & 15);
    int kbase = kk * 32 + (lane >> 4) * 8;
    const float* src = W + ((size_t)bank * DHEAD + kbase) * DMODEL + m;
    short8 o;
    #pragma unroll
    for (int v = 0; v < 8; ++v)
        o[v] = (short)f2bf(src[v * DMODEL]);
    reinterpret_cast<short8*>(wfrag)[t] = o;
}

// Bucket slots by bank with LDS pre-aggregation: 32 blocks x 256 slots.
__global__ void bucket_kernel(const int* __restrict__ sel,
                              int* __restrict__ counts,
                              int* __restrict__ lists) {
    __shared__ int lcount[NBANK];
    __shared__ int lbase[NBANK];
    int tid = threadIdx.x;
    int slot = blockIdx.x * 256 + tid;
    if (tid < NBANK) lcount[tid] = 0;
    __syncthreads();
    int bank = sel[slot];
    int mypos = atomicAdd(&lcount[bank], 1);
    __syncthreads();
    if (tid < NBANK) lbase[tid] = atomicAdd(&counts[tid], lcount[tid]);
    __syncthreads();
    lists[bank * NSLOT + lbase[bank] + mypos] = slot;
}

// Compact: xc[bank][pos][:] = bf16(p * x[lists[bank][pos]][:]).
// One wave per row; 64 lanes x 8B fp32 read, 4B bf16 write. Rows beyond cnt
// stay poisoned -- harmless (tiny bf16 values feed discarded D rows only).
__global__ void compact_kernel(const float* __restrict__ x,
                               const float* __restrict__ probs,
                               const int* __restrict__ counts,
                               const int* __restrict__ lists,
                               unsigned short* __restrict__ xc) {
    int bank = blockIdx.x;
    int wv = (threadIdx.x >> 6) + blockIdx.y * 4;  // 0..15
    int lane = threadIdx.x & 63;
    int cnt = counts[bank];
    for (int pos = wv; pos < cnt; pos += 16) {
        int slot = lists[bank * NSLOT + pos];
        float p = probs[slot];
        float2 v = reinterpret_cast<const float2*>(x + (size_t)slot * DHEAD)[lane];
        ushort2 o;
        o.x = f2bf(v.x * p);
        o.y = f2bf(v.y * p);
        reinterpret_cast<ushort2*>(xc + ((size_t)bank * XCROWS + pos) * DHEAD)[lane] = o;
    }
}

// Grouped GEMM: grid = (m-blocks=8, banks=32, row-split=4), 256 threads.
// Per wave: 64 m-cols, W fragments bw[4][4] resident. A-tile (16 rows x 128k)
// staged by global_load_lds (16B/thread) with the XOR swizzle folded into the
// per-lane GLOBAL source address (LDS dest stays linear). Per-slot bf16 proj
// rows out -- exclusive ownership, no atomics.
__global__ __launch_bounds__(256, 4)
void gemm_kernel(const unsigned short* __restrict__ wfrag,
                 const unsigned short* __restrict__ xc,
                 const int* __restrict__ counts,
                 const int* __restrict__ lists,
                 unsigned short* __restrict__ proj) {
    __shared__ __align__(16) unsigned short A_lds[16 * DHEAD]; // 4 KB
    __shared__ int slots_lds[16];

    int tid = threadIdx.x;
    int w = tid >> 6;          // wave 0..3
    int lane = tid & 63;
    int lane_lo = lane & 15;   // MFMA: A row / B col / D col
    int lane_hi = lane >> 4;   // MFMA: k-group / D row-group
    int bank = blockIdx.y;
    int mw = blockIdx.x * 256 + w * 64;  // this wave's 64-col m-slice
    int mt0 = mw >> 4;                   // first 16-col tile index
    int cnt = counts[bank];

    // ---- Preload W fragments: 16 coalesced 16B loads per lane ----
    const short8* wf = reinterpret_cast<const short8*>(wfrag);
    short8 bw[4][4];   // [kk][nf]
    #pragma unroll
    for (int nf = 0; nf < 4; ++nf)
        #pragma unroll
        for (int kk = 0; kk < 4; ++kk)
            bw[kk][nf] = wf[((((bank * 128 + mt0 + nf) * 4) + kk) << 6) + lane];

    // Staging source: thread t fetches chunk (j ^ (row&7)) of row (t>>4) so
    // that the LINEAR LDS dest (t*16) holds the swizzled layout the ds_read
    // expects: LDS[row*256 + j*16] = row bytes [(j^(row&7))*16 ...).
    int row16 = tid >> 4, j = tid & 15;
    const char* xc_b = reinterpret_cast<const char*>(xc)
                     + ((size_t)bank * XCROWS + row16) * 256
                     + ((j ^ (row16 & 7)) << 4);
    char* lds_b = reinterpret_cast<char*>(A_lds);
    char* lds_dst = lds_b + (w << 10);   // wave-uniform; lane adds lane*16

    for (int rt = blockIdx.z; rt * 16 < cnt; rt += 4) {
        __syncthreads();   // protect previous iter's A_lds/slots_lds readers
        __builtin_amdgcn_global_load_lds(
            (const __attribute__((address_space(1))) void*)(xc_b + (size_t)rt * 16 * 256),
            (__attribute__((address_space(3))) void*)lds_dst, 16, 0, 0);
        if (tid < 16) {
            int ridx = rt * 16 + tid;
            slots_lds[tid] = (ridx < cnt) ? lists[bank * NSLOT + ridx] : -1;
        }
        __syncthreads();   // compiler drains vmcnt/lgkmcnt before barrier

        f32x4 acc[4] = {{0.f,0.f,0.f,0.f},{0.f,0.f,0.f,0.f},
                        {0.f,0.f,0.f,0.f},{0.f,0.f,0.f,0.f}};
        #pragma unroll
        for (int kk = 0; kk < 4; ++kk) {
            // A-frag: row = lane&15, k = kk*32 + 8*(lane>>4) + v (16B contiguous)
            int byteoff = lane_lo * 256 +
                          ((kk * 64 + lane_hi * 16) ^ ((lane_lo & 7) << 4));
            short8 a = *reinterpret_cast<const short8*>(lds_b + byteoff);
            #pragma unroll
            for (int nf = 0; nf < 4; ++nf)
                acc[nf] = __builtin_amdgcn_mfma_f32_16x16x32_bf16(
                              a, bw[kk][nf], acc[nf], 0, 0, 0);
        }

        // Epilogue: D[row][col], col = lane&15, row = 4*(lane>>4)+v.
        #pragma unroll
        for (int v = 0; v < 4; ++v) {
            int row = lane_hi * 4 + v;
            int slot = slots_lds[row];
            if (slot >= 0) {
                unsigned short* pr = proj + (size_t)slot * DMODEL + mw + lane_lo;
                #pragma unroll
                for (int nf = 0; nf < 4; ++nf)
                    pr[nf * 16] = f2bf(acc[nf][v]);
            }
        }
    }
}

// Merge: out[tok][m] = sum_k proj[tok*4+k][m] + p_k * bias[sel_k][m].
// 2048 blocks x 256 threads; thread owns 8 consecutive m-columns (32B).
__global__ void merge_kernel(const unsigned short* __restrict__ proj,
                             const int* __restrict__ sel,
                             const float* __restrict__ probs,
                             const float* __restrict__ bias,
                             float* __restrict__ out) {
    int tid = threadIdx.x;
    int tok = blockIdx.x;
    float8 acc = {0.f, 0.f, 0.f, 0.f, 0.f, 0.f, 0.f, 0.f};
    #pragma unroll
    for (int k = 0; k < 4; ++k) {
        int slot = tok * 4 + k;
        short8 pr = reinterpret_cast<const short8*>(proj + (size_t)slot * DMODEL)[tid];
        float p = probs[slot];
        int bk = sel[slot];
        float8 bv = reinterpret_cast<const float8*>(bias + (size_t)bk * DMODEL)[tid];
        #pragma unroll
        for (int jj = 0; jj < 8; ++jj)
            acc[jj] += bf2f((unsigned short)pr[jj]) + p * bv[jj];
    }
    reinterpret_cast<float8*>(out + (size_t)tok * DMODEL)[tid] = acc;
}

extern "C" void kernel_launch(void* const* d_in, const int* in_sizes, int n_in,
                              void* d_out, int out_size, void* d_ws, size_t ws_size,
                              hipStream_t stream) {
    const float* x     = (const float*)d_in[0];  // (2,1024,4,128)
    const int*   sel   = (const int*)  d_in[1];  // (2,1024,4)
    const float* probs = (const float*)d_in[2];  // (2,1024,4)
    const float* W     = (const float*)d_in[3];  // (32,128,2048)
    const float* bias  = (const float*)d_in[4];  // (32,2048)
    float* out = (float*)d_out;                  // (2,1024,2048) fp32

    // ws layout (~65.5 MB):
    //   [0,128)          counts (32 ints, zeroed each call)
    //   [1024, ~1.05MB)  lists  (32 x 8192 ints)
    //   [2MB,  10MB)     xc     (32 x 1024 x 128 bf16, bank-compacted p*x)
    //   [12MB, ~28.8MB)  wfrag  (32x128x2048 bf16, fragment-swizzled)
    //   [32MB, ~65.6MB)  proj   (8192 x 2048 bf16)
    char* ws = (char*)d_ws;
    int* counts = (int*)ws;
    int* lists  = (int*)(ws + 1024);
    unsigned short* xc    = (unsigned short*)(ws + (2u  << 20));
    unsigned short* wfrag = (unsigned short*)(ws + (12u << 20));
    unsigned short* proj  = (unsigned short*)(ws + (32u << 20));

    hipMemsetAsync(counts, 0, 128, stream);
    convW_kernel<<<4096, 256, 0, stream>>>(W, wfrag);
    bucket_kernel<<<32, 256, 0, stream>>>(sel, counts, lists);
    compact_kernel<<<dim3(32, 4), 256, 0, stream>>>(x, probs, counts, lists, xc);
    gemm_kernel<<<dim3(8, 32, 4), 256, 0, stream>>>(wfrag, xc, counts, lists, proj);
    merge_kernel<<<2048, 256, 0, stream>>>(proj, sel, probs, bias, out);
}

// Round 9
// 128.710 us; speedup vs baseline: 1.0302x; 1.0302x over previous
//
#include <hip/hip_runtime.h>
#include <hip/hip_bf16.h>

#define NBANK 32
#define DHEAD 128
#define DMODEL 2048
#define NSLOT 8192   // B*S*K = 2*1024*4
#define NTOK 2048    // B*S
#define XCROWS 1024  // padded rows per bank (cnt ~256±60 for these inputs)
#define CONV_BLOCKS 4096

typedef __attribute__((ext_vector_type(8))) short short8;
typedef __attribute__((ext_vector_type(8))) float float8;
typedef __attribute__((ext_vector_type(4))) float f32x4;

__device__ __forceinline__ unsigned short f2bf(float f) {
    union { __hip_bfloat16 h; unsigned short u; } cvt;
    cvt.h = __float2bfloat16(f);
    return cvt.u;
}
__device__ __forceinline__ float bf2f(unsigned short u) {
    union { float f; unsigned int v; } cvt;
    cvt.v = ((unsigned int)u) << 16;
    return cvt.f;
}

// Fused prep: blocks [0,4096) convert W fp32 -> bf16 fragment-swizzled layout
//   wfrag[(((bank*128 + mt)*4 + kk)*64 + lane)*8 + v] = W[bank][k][m],
//   m = mt*16 + (lane&15), k = kk*32 + (lane>>4)*8 + v;
// blocks [4096,4128) bucket slots by bank (LDS-aggregated histogram).
// Independent work, one dispatch; whole-block branch = no divergence.
__global__ void prep_kernel(const float* __restrict__ W,
                            unsigned short* __restrict__ wfrag,
                            const int* __restrict__ sel,
                            int* __restrict__ counts,
                            int* __restrict__ lists) {
    if (blockIdx.x < CONV_BLOCKS) {
        int t = blockIdx.x * 256 + threadIdx.x;   // (bank,mt,kk,lane)
        int lane = t & 63;
        int kk = (t >> 6) & 3;
        int mt = (t >> 8) & 127;
        int bank = t >> 15;
        int m = mt * 16 + (lane & 15);
        int kbase = kk * 32 + (lane >> 4) * 8;
        const float* src = W + ((size_t)bank * DHEAD + kbase) * DMODEL + m;
        short8 o;
        #pragma unroll
        for (int v = 0; v < 8; ++v)
            o[v] = (short)f2bf(src[v * DMODEL]);
        reinterpret_cast<short8*>(wfrag)[t] = o;
    } else {
        __shared__ int lcount[NBANK];
        __shared__ int lbase[NBANK];
        int tid = threadIdx.x;
        int slot = (blockIdx.x - CONV_BLOCKS) * 256 + tid;
        if (tid < NBANK) lcount[tid] = 0;
        __syncthreads();
        int bank = sel[slot];
        int mypos = atomicAdd(&lcount[bank], 1);
        __syncthreads();
        if (tid < NBANK) lbase[tid] = atomicAdd(&counts[tid], lcount[tid]);
        __syncthreads();
        lists[bank * NSLOT + lbase[bank] + mypos] = slot;
    }
}

// Compact: xc[bank][pos][:] = bf16(p * x[lists[bank][pos]][:]).
// One wave per row; rows beyond cnt stay poisoned (harmless: they feed only
// discarded D rows).
__global__ void compact_kernel(const float* __restrict__ x,
                               const float* __restrict__ probs,
                               const int* __restrict__ counts,
                               const int* __restrict__ lists,
                               unsigned short* __restrict__ xc) {
    int bank = blockIdx.x;
    int wv = (threadIdx.x >> 6) + blockIdx.y * 4;  // 0..15
    int lane = threadIdx.x & 63;
    int cnt = min(counts[bank], XCROWS);
    for (int pos = wv; pos < cnt; pos += 16) {
        int slot = lists[bank * NSLOT + pos];
        float p = probs[slot];
        float2 v = reinterpret_cast<const float2*>(x + (size_t)slot * DHEAD)[lane];
        ushort2 o;
        o.x = f2bf(v.x * p);
        o.y = f2bf(v.y * p);
        reinterpret_cast<ushort2*>(xc + ((size_t)bank * XCROWS + pos) * DHEAD)[lane] = o;
    }
}

// Grouped GEMM: grid = (m-blocks=16, banks=32, z=2), 256 threads.
// R6-PROVEN inner structure: single LDS buffer, two barriers per tile, stage
// between them via global_load_lds (swizzle folded into per-lane GLOBAL source,
// linear LDS dest), slots_lds + slot-indexed proj epilogue. Geometry deltas
// only: wave owns 32 m-cols (bw[4][2] resident = 32 VGPR), z=2 (W read 2x,
// 8 tiles/block, 1024 blocks = 4/CU for inter-block latency overlap).
__global__ __launch_bounds__(256, 4)
void gemm_kernel(const unsigned short* __restrict__ wfrag,
                 const unsigned short* __restrict__ xc,
                 const int* __restrict__ counts,
                 const int* __restrict__ lists,
                 unsigned short* __restrict__ proj) {
    __shared__ __align__(16) unsigned short A_lds[16 * DHEAD]; // 4 KB
    __shared__ int slots_lds[16];

    int tid = threadIdx.x;
    int w = tid >> 6;          // wave 0..3
    int lane = tid & 63;
    int lane_lo = lane & 15;   // MFMA: A row / B col / D col
    int lane_hi = lane >> 4;   // MFMA: k-group / D row-group
    int bank = blockIdx.y;
    int mw = blockIdx.x * 128 + w * 32;  // this wave's 32-col m-slice
    int mt0 = mw >> 4;                   // first 16-col tile index
    int cnt = min(counts[bank], XCROWS);

    // ---- Preload W fragments: 8 coalesced 16B loads per lane ----
    const short8* wf = reinterpret_cast<const short8*>(wfrag);
    short8 bw[4][2];   // [kk][nf]
    #pragma unroll
    for (int nf = 0; nf < 2; ++nf)
        #pragma unroll
        for (int kk = 0; kk < 4; ++kk)
            bw[kk][nf] = wf[((((bank * 128 + mt0 + nf) * 4) + kk) << 6) + lane];

    // Staging source: thread t fetches chunk (j ^ (row&7)) of row (t>>4) so
    // the LINEAR LDS dest (t*16) holds the swizzled layout the ds_read wants.
    int row16 = tid >> 4, j = tid & 15;
    const char* xc_b = reinterpret_cast<const char*>(xc)
                     + ((size_t)bank * XCROWS + row16) * 256
                     + ((j ^ (row16 & 7)) << 4);
    char* lds_b = reinterpret_cast<char*>(A_lds);
    char* lds_dst = lds_b + (w << 10);   // wave-uniform; HW adds lane*16

    for (int rt = blockIdx.z; rt * 16 < cnt; rt += 2) {
        __syncthreads();   // protect previous iter's A_lds/slots_lds readers
        __builtin_amdgcn_global_load_lds(
            (const __attribute__((address_space(1))) void*)(xc_b + (size_t)rt * 4096),
            (__attribute__((address_space(3))) void*)lds_dst, 16, 0, 0);
        if (tid < 16) {
            int ridx = rt * 16 + tid;
            slots_lds[tid] = (ridx < cnt) ? lists[bank * NSLOT + ridx] : -1;
        }
        __syncthreads();   // compiler drains vmcnt/lgkmcnt before barrier

        f32x4 acc0 = {0.f, 0.f, 0.f, 0.f};
        f32x4 acc1 = {0.f, 0.f, 0.f, 0.f};
        #pragma unroll
        for (int kk = 0; kk < 4; ++kk) {
            // A-frag: row = lane&15, k = kk*32 + 8*(lane>>4) + v (16B contiguous)
            int byteoff = lane_lo * 256 +
                          ((kk * 64 + lane_hi * 16) ^ ((lane_lo & 7) << 4));
            short8 a = *reinterpret_cast<const short8*>(lds_b + byteoff);
            acc0 = __builtin_amdgcn_mfma_f32_16x16x32_bf16(a, bw[kk][0], acc0, 0, 0, 0);
            acc1 = __builtin_amdgcn_mfma_f32_16x16x32_bf16(a, bw[kk][1], acc1, 0, 0, 0);
        }

        // Epilogue: D[row][col], col = lane&15, row = 4*(lane>>4)+v.
        #pragma unroll
        for (int v = 0; v < 4; ++v) {
            int row = lane_hi * 4 + v;
            int slot = slots_lds[row];
            if (slot >= 0) {
                unsigned short* pr = proj + (size_t)slot * DMODEL + mw + lane_lo;
                pr[0]  = f2bf(acc0[v]);
                pr[16] = f2bf(acc1[v]);
            }
        }
    }
}

// Merge: out[tok][m] = sum_k proj[tok*4+k][m] + p_k * bias[sel_k][m].
// 2048 blocks x 256 threads; thread owns 8 consecutive m-columns.
__global__ void merge_kernel(const unsigned short* __restrict__ proj,
                             const int* __restrict__ sel,
                             const float* __restrict__ probs,
                             const float* __restrict__ bias,
                             float* __restrict__ out) {
    int tid = threadIdx.x;
    int tok = blockIdx.x;
    float8 acc = {0.f, 0.f, 0.f, 0.f, 0.f, 0.f, 0.f, 0.f};
    #pragma unroll
    for (int k = 0; k < 4; ++k) {
        int slot = tok * 4 + k;
        short8 pr = reinterpret_cast<const short8*>(proj + (size_t)slot * DMODEL)[tid];
        float p = probs[slot];
        int bk = sel[slot];
        float8 bv = reinterpret_cast<const float8*>(bias + (size_t)bk * DMODEL)[tid];
        #pragma unroll
        for (int jj = 0; jj < 8; ++jj)
            acc[jj] += bf2f((unsigned short)pr[jj]) + p * bv[jj];
    }
    reinterpret_cast<float8*>(out + (size_t)tok * DMODEL)[tid] = acc;
}

extern "C" void kernel_launch(void* const* d_in, const int* in_sizes, int n_in,
                              void* d_out, int out_size, void* d_ws, size_t ws_size,
                              hipStream_t stream) {
    const float* x     = (const float*)d_in[0];  // (2,1024,4,128)
    const int*   sel   = (const int*)  d_in[1];  // (2,1024,4)
    const float* probs = (const float*)d_in[2];  // (2,1024,4)
    const float* W     = (const float*)d_in[3];  // (32,128,2048)
    const float* bias  = (const float*)d_in[4];  // (32,2048)
    float* out = (float*)d_out;                  // (2,1024,2048) fp32

    // ws layout (~65.5 MB):
    //   [0,128)          counts (32 ints, zeroed each call)
    //   [1024, ~1.05MB)  lists  (32 x 8192 ints)
    //   [3MB, 11MB)      xc     (32 x 1024 x 128 bf16, bank-compacted p*x)
    //   [12MB, ~28.8MB)  wfrag  (32x128x2048 bf16, fragment-swizzled)
    //   [32MB, ~65.6MB)  proj   (8192 x 2048 bf16, slot-indexed)
    char* ws = (char*)d_ws;
    int* counts = (int*)ws;
    int* lists  = (int*)(ws + 1024);
    unsigned short* xc    = (unsigned short*)(ws + (3u  << 20));
    unsigned short* wfrag = (unsigned short*)(ws + (12u << 20));
    unsigned short* proj  = (unsigned short*)(ws + (32u << 20));

    hipMemsetAsync(counts, 0, 128, stream);
    prep_kernel<<<CONV_BLOCKS + 32, 256, 0, stream>>>(W, wfrag, sel, counts, lists);
    compact_kernel<<<dim3(32, 4), 256, 0, stream>>>(x, probs, counts, lists, xc);
    gemm_kernel<<<dim3(16, 32, 2), 256, 0, stream>>>(wfrag, xc, counts, lists, proj);
    merge_kernel<<<2048, 256, 0, stream>>>(proj, sel, probs, bias, out);
}